// Round 4
// baseline (803.719 us; speedup 1.0000x reference)
//
#include <hip/hip_runtime.h>

#define NN 50000
#define EE 1600000
#define HC 128
#define EPSV 1e-5f
#define NEGS 0.2f

typedef __bf16 bf16x8 __attribute__((ext_vector_type(8)));
typedef __bf16 bf16x2 __attribute__((ext_vector_type(2)));
typedef float f32x4 __attribute__((ext_vector_type(4)));

static inline int cdiv(int a, int b) { return (a + b - 1) / b; }

__device__ inline float blo(unsigned v) { return __uint_as_float(v << 16); }
__device__ inline float bhi(unsigned v) { return __uint_as_float(v & 0xffff0000u); }
__device__ inline unsigned pkbf(float a, float b) {
  bf16x2 p;
  p.x = (__bf16)a;
  p.y = (__bf16)b;
  return *reinterpret_cast<unsigned*>(&p);
}

// h0 = x @ Wn + bn
__global__ __launch_bounds__(256) void k_h0(const float* __restrict__ x, const float* __restrict__ Wn,
                                            const float* __restrict__ bn, float* __restrict__ h) {
  int idx = blockIdx.x * 256 + threadIdx.x;
  if (idx >= NN * HC) return;
  int n = idx >> 7, ch = idx & 127;
  float s = bn[ch];
  const float* xr = x + n * 16;
#pragma unroll
  for (int f = 0; f < 16; ++f) s += xr[f] * Wn[f * HC + ch];
  h[idx] = s;
}

__global__ __launch_bounds__(256) void k_hist(const int* __restrict__ ei, int* __restrict__ cnt) {
  int e = blockIdx.x * 256 + threadIdx.x;
  if (e < EE) atomicAdd(&cnt[ei[EE + e]], 1);
}

__global__ __launch_bounds__(1024) void k_scan1(const int* __restrict__ cnt, int* __restrict__ tmp,
                                                int* __restrict__ bsum) {
  __shared__ int lds[1024];
  int t = threadIdx.x;
  int i = blockIdx.x * 1024 + t;
  int v = (i < NN) ? cnt[i] : 0;
  lds[t] = v;
  __syncthreads();
  for (int off = 1; off < 1024; off <<= 1) {
    int u = (t >= off) ? lds[t - off] : 0;
    __syncthreads();
    lds[t] += u;
    __syncthreads();
  }
  if (i < NN) tmp[i] = lds[t] - v;
  if (t == 1023) bsum[blockIdx.x] = lds[1023];
}

__global__ void k_scan2(int* bsum, int nb) {
  if (threadIdx.x == 0 && blockIdx.x == 0) {
    int run = 0;
    for (int b = 0; b < nb; ++b) { int q = bsum[b]; bsum[b] = run; run += q; }
  }
}

__global__ __launch_bounds__(1024) void k_scan3(const int* __restrict__ tmp, const int* __restrict__ bsum,
                                                int* __restrict__ row_ptr, int* __restrict__ wr_ptr) {
  int t = threadIdx.x;
  int i = blockIdx.x * 1024 + t;
  if (i < NN) {
    int v = tmp[i] + bsum[blockIdx.x];
    row_ptr[i] = v;
    wr_ptr[i] = v;
  }
  if (i == 0) row_ptr[NN] = EE;
}

// Pc[i*36 + f*4 + h] = (We @ (W_edge[i] . att_e[i]))[f,h],  Pc[i*36+32+h] = be . v_e[:,h]
__global__ __launch_bounds__(128) void k_wcoef(const float* __restrict__ We, const float* __restrict__ be,
                                               const float* __restrict__ Wed, const float* __restrict__ atte,
                                               float* __restrict__ Pc) {
  __shared__ float v[128][4];
  int t = threadIdx.x;
  for (int i = 0; i < 3; ++i) {
#pragma unroll
    for (int hh = 0; hh < 4; ++hh) {
      float s = 0.f;
      for (int hd = 0; hd < 32; ++hd)
        s += Wed[((size_t)i * 128 + t) * 128 + hh * 32 + hd] * atte[i * 128 + hh * 32 + hd];
      v[t][hh] = s;
    }
    __syncthreads();
    if (t < 32) {
      int f = t >> 2, hh = t & 3;
      float s = 0.f;
      for (int c2 = 0; c2 < 128; ++c2) s += We[f * 128 + c2] * v[c2][hh];
      Pc[i * 36 + f * 4 + hh] = s;
    }
    if (t < 4) {
      float s = 0.f;
      for (int c2 = 0; c2 < 128; ++c2) s += be[c2] * v[c2][t];
      Pc[i * 36 + 32 + t] = s;
    }
    __syncthreads();
  }
}

// WgT padded bf16: wgt[i][n][kp] (kp stride 136) = Wg[i][kp][n]
__global__ __launch_bounds__(256) void k_prep(const float* __restrict__ Wg, __bf16* __restrict__ wgt) {
  int idx = blockIdx.x * 256 + threadIdx.x;
  if (idx >= 3 * 128 * 136) return;
  int i = idx / (128 * 136);
  int rem = idx - i * 128 * 136;
  int n = rem / 136, kp = rem - n * 136;
  float v = (kp < 128) ? Wg[(size_t)i * 16384 + kp * 128 + n] : 0.f;
  wgt[idx] = (__bf16)v;
}

// CSR build: 32B record per edge = {src u32, dst u32, attr bf16x8 (16B), pad 8B}
__global__ __launch_bounds__(256) void k_build(const int* __restrict__ ei, const float* __restrict__ ea,
                                               int* __restrict__ wr_ptr, uint4* __restrict__ rec) {
  int e = blockIdx.x * 256 + threadIdx.x;
  if (e >= EE) return;
  int s = ei[e], d = ei[EE + e];
  const float* ar = ea + (size_t)e * 8;
  float4 q0 = *(const float4*)ar;
  float4 q1 = *(const float4*)(ar + 4);
  int pos = atomicAdd(&wr_ptr[d], 1);
  uint4 r0, r1;
  r0.x = (unsigned)s;
  r0.y = (unsigned)d;
  r0.z = pkbf(q0.x, q0.y);
  r0.w = pkbf(q0.z, q0.w);
  r1.x = pkbf(q1.x, q1.y);
  r1.y = pkbf(q1.z, q1.w);
  r1.z = 0;
  r1.w = 0;
  uint4* rp = rec + (size_t)pos * 2;
  rp[0] = r0;
  rp[1] = r1;
}

// per-node self-loop logit (edge part) for all 3 layers: aself_i[n][h] = Pc_i . mean_attr(n) (+bias), 0 if deg==0
__global__ __launch_bounds__(256) void k_selfe(const int* __restrict__ row_ptr, const unsigned* __restrict__ recd,
                                               const float* __restrict__ Pc, float* __restrict__ as0,
                                               float* __restrict__ as1, float* __restrict__ as2) {
  int wid = (blockIdx.x * 256 + threadIdx.x) >> 6;
  if (wid >= NN) return;
  int lane = threadIdx.x & 63;
  int j0 = row_ptr[wid], j1 = row_ptr[wid + 1];
  int f = lane & 7, g = lane >> 3;
  float s = 0.f;
  for (int j = j0 + g; j < j1; j += 8) {
    unsigned q = recd[(size_t)j * 8 + 2 + (f >> 1)];
    s += (f & 1) ? bhi(q) : blo(q);
  }
  s += __shfl_xor(s, 8);
  s += __shfl_xor(s, 16);
  s += __shfl_xor(s, 32);
  int deg = j1 - j0;
  float mean = s / fmaxf((float)deg, 1.f);
  float m[8];
#pragma unroll
  for (int ff = 0; ff < 8; ++ff) m[ff] = __shfl(mean, ff);
  if (lane < 12) {
    int i = lane >> 2, hh = lane & 3;
    float v = Pc[i * 36 + 32 + hh];
#pragma unroll
    for (int ff = 0; ff < 8; ++ff) v += m[ff] * Pc[i * 36 + ff * 4 + hh];
    if (deg == 0) v = 0.f;
    float* dst = (i == 0) ? as0 : (i == 1) ? as1 : as2;
    dst[(size_t)wid * 4 + hh] = v;
  }
}

// Fused LN + bf16 MFMA GEMM + attention head dots. 128 nodes/block, 4 waves, LDS-staged B.
__global__ __launch_bounds__(256) void k_node(const float* __restrict__ h, const float* __restrict__ lng,
                                              const float* __restrict__ lnb, const __bf16* __restrict__ wgt,
                                              const float* __restrict__ atts, const float* __restrict__ attd,
                                              __bf16* __restrict__ xsb, float* __restrict__ asd) {
  __shared__ __bf16 sA[128][136];
  __shared__ __bf16 sB[128][136];
  __shared__ float sAs[128], sAd[128];
  int t = threadIdx.x;
  int n0 = blockIdx.x * 128;
  if (t < 128) {
    sAs[t] = atts[t];
    sAd[t] = attd[t];
  }
  {
    char* bd = (char*)&sB[0][0];
    const char* bs = (const char*)wgt;
    for (int off = t * 16; off < 34816; off += 4096)
      *(uint4*)(bd + off) = *(const uint4*)(bs + off);
  }
  {
    int row = t >> 1, q = t & 1;
    int n = n0 + row;
    float vals[64];
    if (n < NN) {
      const float* hr = h + (size_t)n * HC + q * 64;
#pragma unroll
      for (int j = 0; j < 64; j += 4) {
        float4 vv = *(const float4*)(hr + j);
        vals[j] = vv.x; vals[j + 1] = vv.y; vals[j + 2] = vv.z; vals[j + 3] = vv.w;
      }
    } else {
#pragma unroll
      for (int j = 0; j < 64; ++j) vals[j] = 0.f;
    }
    float sum = 0.f;
#pragma unroll
    for (int j = 0; j < 64; ++j) sum += vals[j];
    sum += __shfl_xor(sum, 1);
    float mu = sum * (1.f / 128.f);
    float sq = 0.f;
#pragma unroll
    for (int j = 0; j < 64; ++j) { float dm = vals[j] - mu; sq += dm * dm; }
    sq += __shfl_xor(sq, 1);
    float rs = rsqrtf(sq * (1.f / 128.f) + EPSV);
    int chb = q * 64;
#pragma unroll
    for (int j = 0; j < 64; j += 2) {
      int ch = chb + j;
      bf16x2 p;
      p.x = (__bf16)((vals[j] - mu) * rs * lng[ch] + lnb[ch]);
      p.y = (__bf16)((vals[j + 1] - mu) * rs * lng[ch + 1] + lnb[ch + 1]);
      *(bf16x2*)&sA[row][ch] = p;
    }
  }
  __syncthreads();
  int lane = t & 63;
  int c15 = lane & 15, g = lane >> 4;
  int m0w = (t >> 6) * 32;
  f32x4 acc[16];
#pragma unroll
  for (int i = 0; i < 16; ++i) acc[i] = (f32x4){0.f, 0.f, 0.f, 0.f};
#pragma unroll
  for (int ks = 0; ks < 4; ++ks) {
    bf16x8 a0 = *(const bf16x8*)&sA[m0w + c15][ks * 32 + g * 8];
    bf16x8 a1 = *(const bf16x8*)&sA[m0w + 16 + c15][ks * 32 + g * 8];
#pragma unroll
    for (int nt = 0; nt < 8; ++nt) {
      bf16x8 bv = *(const bf16x8*)&sB[nt * 16 + c15][ks * 32 + g * 8];
      acc[nt] = __builtin_amdgcn_mfma_f32_16x16x32_bf16(a0, bv, acc[nt], 0, 0, 0);
      acc[8 + nt] = __builtin_amdgcn_mfma_f32_16x16x32_bf16(a1, bv, acc[8 + nt], 0, 0, 0);
    }
  }
#pragma unroll
  for (int mt = 0; mt < 2; ++mt) {
    int nbase = n0 + m0w + mt * 16 + g * 4;
#pragma unroll
    for (int r = 0; r < 4; ++r) {
      int n = nbase + r;
      float ps[4], pd[4];
#pragma unroll
      for (int hh = 0; hh < 4; ++hh) {
        float w0 = sAs[hh * 32 + c15], w1 = sAs[hh * 32 + 16 + c15];
        float d0 = sAd[hh * 32 + c15], d1 = sAd[hh * 32 + 16 + c15];
        float x0 = acc[mt * 8 + 2 * hh][r], x1 = acc[mt * 8 + 2 * hh + 1][r];
        ps[hh] = x0 * w0 + x1 * w1;
        pd[hh] = x0 * d0 + x1 * d1;
      }
#pragma unroll
      for (int m = 1; m < 16; m <<= 1) {
#pragma unroll
        for (int hh = 0; hh < 4; ++hh) {
          ps[hh] += __shfl_xor(ps[hh], m);
          pd[hh] += __shfl_xor(pd[hh], m);
        }
      }
      if (n < NN) {
        if (c15 == 0) {
          *(float4*)(asd + (size_t)n * 8) = make_float4(ps[0], ps[1], ps[2], ps[3]);
          *(float4*)(asd + (size_t)n * 8 + 4) = make_float4(pd[0], pd[1], pd[2], pd[3]);
        }
        __bf16* op = xsb + (size_t)n * HC + c15;
#pragma unroll
        for (int nt = 0; nt < 8; ++nt) op[nt * 16] = (__bf16)acc[mt * 8 + nt][r];
      }
    }
  }
}

// thread per edge: full score -> ex4 (f32 x 4 heads). Layer 0 also extracts csr_src stream.
__global__ __launch_bounds__(256) void k_score(const uint4* __restrict__ rec, const float* __restrict__ asd,
                                               const float* __restrict__ Pc, float* __restrict__ ex4,
                                               int* __restrict__ csr_src_out) {
  __shared__ float P[36];
  if (threadIdx.x < 36) P[threadIdx.x] = Pc[threadIdx.x];
  __syncthreads();
  int j = blockIdx.x * 256 + threadIdx.x;
  if (j >= EE) return;
  uint4 r0 = rec[(size_t)j * 2];
  uint4 r1 = rec[(size_t)j * 2 + 1];
  int s = (int)r0.x, d = (int)r0.y;
  float a[8] = {blo(r0.z), bhi(r0.z), blo(r0.w), bhi(r0.w), blo(r1.x), bhi(r1.x), blo(r1.y), bhi(r1.y)};
  float4 asv = *(const float4*)(asd + (size_t)s * 8);
  float4 adv = *(const float4*)(asd + (size_t)d * 8 + 4);
  float asa[4] = {asv.x, asv.y, asv.z, asv.w};
  float ada[4] = {adv.x, adv.y, adv.z, adv.w};
  float eh[4];
#pragma unroll
  for (int hh = 0; hh < 4; ++hh) {
    float ae = P[32 + hh];
#pragma unroll
    for (int f = 0; f < 8; ++f) ae += a[f] * P[f * 4 + hh];
    float al = asa[hh] + ada[hh] + ae;
    al = al > 0.f ? al : NEGS * al;
    eh[hh] = __expf(al);
  }
  *(float4*)(ex4 + (size_t)j * 4) = make_float4(eh[0], eh[1], eh[2], eh[3]);
  if (csr_src_out) csr_src_out[j] = s;
}

// wave per node: aggregate Sum(ex*xs[src]), Sum(ex); self-loop; divide; h += relu; optional emb accumulate
__global__ __launch_bounds__(256) void k_aggr(const int* __restrict__ row_ptr, const int* __restrict__ csr_src,
                                              const float* __restrict__ ex4, const __bf16* __restrict__ xsb,
                                              const float* __restrict__ asd, const float* __restrict__ aself,
                                              const float* __restrict__ bgi, float* __restrict__ h,
                                              float* __restrict__ emb) {
  int tid = threadIdx.x;
  int wid = (blockIdx.x * 256 + tid) >> 6;   // grid exact: NN % 4 == 0
  int lane = tid & 63;
  int ch0 = 2 * lane, head = lane >> 4;
  int j0 = row_ptr[wid], j1 = row_ptr[wid + 1];
  float acc0 = 0.f, acc1 = 0.f, dsum = 0.f;
  int j = j0;
  for (; j + 8 <= j1; j += 8) {
    int ss[8];
    float ev[8];
    unsigned xv[8];
#pragma unroll
    for (int u = 0; u < 8; ++u) ss[u] = csr_src[j + u];
#pragma unroll
    for (int u = 0; u < 8; ++u) ev[u] = ex4[(size_t)(j + u) * 4 + head];
#pragma unroll
    for (int u = 0; u < 8; ++u) xv[u] = *(const unsigned*)(xsb + (size_t)ss[u] * HC + ch0);
#pragma unroll
    for (int u = 0; u < 8; ++u) {
      acc0 += ev[u] * blo(xv[u]);
      acc1 += ev[u] * bhi(xv[u]);
      dsum += ev[u];
    }
  }
  for (; j < j1; ++j) {
    int s0 = csr_src[j];
    float e0 = ex4[(size_t)j * 4 + head];
    unsigned x0 = *(const unsigned*)(xsb + (size_t)s0 * HC + ch0);
    acc0 += e0 * blo(x0);
    acc1 += e0 * bhi(x0);
    dsum += e0;
  }
  float as_w = asd[(size_t)wid * 8 + head];
  float ad_w = asd[(size_t)wid * 8 + 4 + head];
  float al = as_w + ad_w + aself[(size_t)wid * 4 + head];
  al = al > 0.f ? al : NEGS * al;
  float exl = __expf(al);
  unsigned xv = *(const unsigned*)(xsb + (size_t)wid * HC + ch0);
  float inv = 1.f / (dsum + exl);
  float o0 = (acc0 + exl * blo(xv)) * inv;
  float o1 = (acc1 + exl * bhi(xv)) * inv;
  float* hp = h + (size_t)wid * HC;
  float n0v = hp[ch0] + fmaxf(0.f, o0 + bgi[ch0]);
  float n1v = hp[ch0 + 1] + fmaxf(0.f, o1 + bgi[ch0 + 1]);
  hp[ch0] = n0v;
  hp[ch0 + 1] = n1v;
  if (emb) {
    __shared__ float se[128];
    if (tid < 128) se[tid] = 0.f;
    __syncthreads();
    atomicAdd(&se[ch0], n0v);
    atomicAdd(&se[ch0 + 1], n1v);
    __syncthreads();
    if (tid < 128) atomicAdd(&emb[tid], se[tid] * (1.f / NN));
  }
}

extern "C" void kernel_launch(void* const* d_in, const int* in_sizes, int n_in, void* d_out, int out_size,
                              void* d_ws, size_t ws_size, hipStream_t stream) {
  (void)in_sizes; (void)n_in; (void)out_size; (void)ws_size;
  const float* x = (const float*)d_in[0];
  const int* ei = (const int*)d_in[1];
  const float* ea = (const float*)d_in[2];
  const float* Wn = (const float*)d_in[3];
  const float* bn = (const float*)d_in[4];
  const float* We = (const float*)d_in[5];
  const float* be = (const float*)d_in[6];
  const float* lng = (const float*)d_in[7];
  const float* lnb = (const float*)d_in[8];
  const float* Wg = (const float*)d_in[9];
  const float* atts = (const float*)d_in[10];
  const float* attd = (const float*)d_in[11];
  const float* atte = (const float*)d_in[12];
  const float* Wed = (const float*)d_in[13];
  const float* bg = (const float*)d_in[14];
  float* h = (float*)d_out;
  float* emb = h + (size_t)NN * HC;

  char* w = (char*)d_ws;
  size_t off = 0;
  auto alloc = [&](size_t bytes) {
    void* p = w + off;
    off = (off + bytes + 255) & ~(size_t)255;
    return p;
  };
  __bf16* xsb = (__bf16*)alloc((size_t)NN * HC * 2);
  float* asd = (float*)alloc((size_t)NN * 8 * 4);
  int* cnt = (int*)alloc((size_t)NN * 4);
  int* row_ptr = (int*)alloc((size_t)(NN + 1) * 4);
  int* wr_ptr = (int*)alloc((size_t)NN * 4);
  int* bsum = (int*)alloc(256);
  int* stmp = (int*)alloc((size_t)NN * 4);
  uint4* rec = (uint4*)alloc((size_t)EE * 32);
  float* ex4 = (float*)alloc((size_t)EE * 4 * 4);
  int* csr_src = (int*)alloc((size_t)EE * 4);
  float* aself0 = (float*)alloc((size_t)NN * 4 * 4);
  float* aself1 = (float*)alloc((size_t)NN * 4 * 4);
  float* aself2 = (float*)alloc((size_t)NN * 4 * 4);
  float* Pc = (float*)alloc(3 * 36 * 4);
  __bf16* wgt = (__bf16*)alloc((size_t)3 * 128 * 136 * 2);
  float* aselfp[3] = {aself0, aself1, aself2};

  hipMemsetAsync(cnt, 0, (size_t)NN * 4, stream);
  hipMemsetAsync(emb, 0, HC * 4, stream);

  k_h0<<<cdiv(NN * HC, 256), 256, 0, stream>>>(x, Wn, bn, h);
  k_hist<<<cdiv(EE, 256), 256, 0, stream>>>(ei, cnt);
  int nb = cdiv(NN, 1024);
  k_scan1<<<nb, 1024, 0, stream>>>(cnt, stmp, bsum);
  k_scan2<<<1, 64, 0, stream>>>(bsum, nb);
  k_scan3<<<nb, 1024, 0, stream>>>(stmp, bsum, row_ptr, wr_ptr);
  k_wcoef<<<1, 128, 0, stream>>>(We, be, Wed, atte, Pc);
  k_prep<<<cdiv(3 * 128 * 136, 256), 256, 0, stream>>>(Wg, wgt);
  k_build<<<cdiv(EE, 256), 256, 0, stream>>>(ei, ea, wr_ptr, rec);
  k_selfe<<<cdiv(NN, 4), 256, 0, stream>>>(row_ptr, (const unsigned*)rec, Pc, aself0, aself1, aself2);

  for (int i = 0; i < 3; ++i) {
    k_node<<<cdiv(NN, 128), 256, 0, stream>>>(h, lng + i * HC, lnb + i * HC, wgt + (size_t)i * 128 * 136,
                                              atts + i * HC, attd + i * HC, xsb, asd);
    k_score<<<cdiv(EE, 256), 256, 0, stream>>>(rec, asd, Pc + i * 36, ex4, (i == 0) ? csr_src : nullptr);
    k_aggr<<<NN / 4, 256, 0, stream>>>(row_ptr, csr_src, ex4, xsb, asd, aselfp[i], bg + i * HC, h,
                                       (i == 2) ? emb : nullptr);
  }
}

// Round 5
// 534.568 us; speedup vs baseline: 1.5035x; 1.5035x over previous
//
#include <hip/hip_runtime.h>

#define NN 50000
#define EE 1600000
#define HC 128
#define EPSV 1e-5f
#define NEGS 0.2f

typedef __bf16 bf16x8 __attribute__((ext_vector_type(8)));
typedef __bf16 bf16x2 __attribute__((ext_vector_type(2)));
typedef float f32x4 __attribute__((ext_vector_type(4)));

static inline int cdiv(int a, int b) { return (a + b - 1) / b; }

__device__ inline float blo(unsigned v) { return __uint_as_float(v << 16); }
__device__ inline float bhi(unsigned v) { return __uint_as_float(v & 0xffff0000u); }
__device__ inline unsigned pkbf(float a, float b) {
  bf16x2 p;
  p.x = (__bf16)a;
  p.y = (__bf16)b;
  return *reinterpret_cast<unsigned*>(&p);
}

// h0 = x @ Wn + bn
__global__ __launch_bounds__(256) void k_h0(const float* __restrict__ x, const float* __restrict__ Wn,
                                            const float* __restrict__ bn, float* __restrict__ h) {
  int idx = blockIdx.x * 256 + threadIdx.x;
  if (idx >= NN * HC) return;
  int n = idx >> 7, ch = idx & 127;
  float s = bn[ch];
  const float* xr = x + n * 16;
#pragma unroll
  for (int f = 0; f < 16; ++f) s += xr[f] * Wn[f * HC + ch];
  h[idx] = s;
}

__global__ __launch_bounds__(256) void k_hist(const int* __restrict__ ei, int* __restrict__ cnt) {
  int e = blockIdx.x * 256 + threadIdx.x;
  if (e < EE) atomicAdd(&cnt[ei[EE + e]], 1);
}

__global__ __launch_bounds__(1024) void k_scan1(const int* __restrict__ cnt, int* __restrict__ tmp,
                                                int* __restrict__ bsum) {
  __shared__ int lds[1024];
  int t = threadIdx.x;
  int i = blockIdx.x * 1024 + t;
  int v = (i < NN) ? cnt[i] : 0;
  lds[t] = v;
  __syncthreads();
  for (int off = 1; off < 1024; off <<= 1) {
    int u = (t >= off) ? lds[t - off] : 0;
    __syncthreads();
    lds[t] += u;
    __syncthreads();
  }
  if (i < NN) tmp[i] = lds[t] - v;
  if (t == 1023) bsum[blockIdx.x] = lds[1023];
}

__global__ void k_scan2(int* bsum, int nb) {
  if (threadIdx.x == 0 && blockIdx.x == 0) {
    int run = 0;
    for (int b = 0; b < nb; ++b) { int q = bsum[b]; bsum[b] = run; run += q; }
  }
}

__global__ __launch_bounds__(1024) void k_scan3(const int* __restrict__ tmp, const int* __restrict__ bsum,
                                                int* __restrict__ row_ptr, int* __restrict__ wr_ptr) {
  int t = threadIdx.x;
  int i = blockIdx.x * 1024 + t;
  if (i < NN) {
    int v = tmp[i] + bsum[blockIdx.x];
    row_ptr[i] = v;
    wr_ptr[i] = v;
  }
  if (i == 0) row_ptr[NN] = EE;
}

// Pc[i*36 + f*4 + h] = (We @ (W_edge[i] . att_e[i]))[f,h],  Pc[i*36+32+h] = be . v_e[:,h]
__global__ __launch_bounds__(128) void k_wcoef(const float* __restrict__ We, const float* __restrict__ be,
                                               const float* __restrict__ Wed, const float* __restrict__ atte,
                                               float* __restrict__ Pc) {
  __shared__ float v[128][4];
  int t = threadIdx.x;
  for (int i = 0; i < 3; ++i) {
#pragma unroll
    for (int hh = 0; hh < 4; ++hh) {
      float s = 0.f;
      for (int hd = 0; hd < 32; ++hd)
        s += Wed[((size_t)i * 128 + t) * 128 + hh * 32 + hd] * atte[i * 128 + hh * 32 + hd];
      v[t][hh] = s;
    }
    __syncthreads();
    if (t < 32) {
      int f = t >> 2, hh = t & 3;
      float s = 0.f;
      for (int c2 = 0; c2 < 128; ++c2) s += We[f * 128 + c2] * v[c2][hh];
      Pc[i * 36 + f * 4 + hh] = s;
    }
    if (t < 4) {
      float s = 0.f;
      for (int c2 = 0; c2 < 128; ++c2) s += be[c2] * v[c2][t];
      Pc[i * 36 + 32 + t] = s;
    }
    __syncthreads();
  }
}

// WgT padded bf16: wgt[i][n][kp] (kp stride 136) = Wg[i][kp][n]
__global__ __launch_bounds__(256) void k_prep(const float* __restrict__ Wg, __bf16* __restrict__ wgt) {
  int idx = blockIdx.x * 256 + threadIdx.x;
  if (idx >= 3 * 128 * 136) return;
  int i = idx / (128 * 136);
  int rem = idx - i * 128 * 136;
  int n = rem / 136, kp = rem - n * 136;
  float v = (kp < 128) ? Wg[(size_t)i * 16384 + kp * 128 + n] : 0.f;
  wgt[idx] = (__bf16)v;
}

// CSR build: single 32B record per edge = {src, ae[l0][h01], ae[l0][h23], ae[l1][h01], ae[l1][h23],
//                                          ae[l2][h01], ae[l2][h23], pad} (bf16 pairs)
__global__ __launch_bounds__(256) void k_build(const int* __restrict__ ei, const float* __restrict__ ea,
                                               const float* __restrict__ Pc, int* __restrict__ wr_ptr,
                                               uint4* __restrict__ rec) {
  __shared__ float P[108];
  if (threadIdx.x < 108) P[threadIdx.x] = Pc[threadIdx.x];
  __syncthreads();
  int e = blockIdx.x * 256 + threadIdx.x;
  if (e >= EE) return;
  int s = ei[e], d = ei[EE + e];
  const float* ar = ea + (size_t)e * 8;
  float4 q0 = *(const float4*)ar;
  float4 q1 = *(const float4*)(ar + 4);
  float a[8] = {q0.x, q0.y, q0.z, q0.w, q1.x, q1.y, q1.z, q1.w};
  float r[3][4];
#pragma unroll
  for (int i = 0; i < 3; ++i) {
    const float* p = P + i * 36;
#pragma unroll
    for (int hh = 0; hh < 4; ++hh) {
      float s2 = p[32 + hh];
#pragma unroll
      for (int f = 0; f < 8; ++f) s2 += a[f] * p[f * 4 + hh];
      r[i][hh] = s2;
    }
  }
  int pos = atomicAdd(&wr_ptr[d], 1);
  uint4 r0, r1;
  r0.x = (unsigned)s;
  r0.y = pkbf(r[0][0], r[0][1]);
  r0.z = pkbf(r[0][2], r[0][3]);
  r0.w = pkbf(r[1][0], r[1][1]);
  r1.x = pkbf(r[1][2], r[1][3]);
  r1.y = pkbf(r[2][0], r[2][1]);
  r1.z = pkbf(r[2][2], r[2][3]);
  r1.w = 0;
  uint4* rp = rec + (size_t)pos * 2;
  rp[0] = r0;
  rp[1] = r1;
}

// Fused LN + bf16 MFMA GEMM + attention head dots. 128 nodes/block, 4 waves, LDS-staged B.
__global__ __launch_bounds__(256) void k_node(const float* __restrict__ h, const float* __restrict__ lng,
                                              const float* __restrict__ lnb, const __bf16* __restrict__ wgt,
                                              const float* __restrict__ atts, const float* __restrict__ attd,
                                              __bf16* __restrict__ xsb, float* __restrict__ asrc,
                                              float* __restrict__ adst) {
  __shared__ __bf16 sA[128][136];
  __shared__ __bf16 sB[128][136];
  __shared__ float sAs[128], sAd[128];
  int t = threadIdx.x;
  int n0 = blockIdx.x * 128;
  if (t < 128) {
    sAs[t] = atts[t];
    sAd[t] = attd[t];
  }
  {
    char* bd = (char*)&sB[0][0];
    const char* bs = (const char*)wgt;
    for (int off = t * 16; off < 34816; off += 4096)
      *(uint4*)(bd + off) = *(const uint4*)(bs + off);
  }
  {
    int row = t >> 1, q = t & 1;
    int n = n0 + row;
    float vals[64];
    if (n < NN) {
      const float* hr = h + (size_t)n * HC + q * 64;
#pragma unroll
      for (int j = 0; j < 64; j += 4) {
        float4 vv = *(const float4*)(hr + j);
        vals[j] = vv.x; vals[j + 1] = vv.y; vals[j + 2] = vv.z; vals[j + 3] = vv.w;
      }
    } else {
#pragma unroll
      for (int j = 0; j < 64; ++j) vals[j] = 0.f;
    }
    float sum = 0.f;
#pragma unroll
    for (int j = 0; j < 64; ++j) sum += vals[j];
    sum += __shfl_xor(sum, 1);
    float mu = sum * (1.f / 128.f);
    float sq = 0.f;
#pragma unroll
    for (int j = 0; j < 64; ++j) { float dm = vals[j] - mu; sq += dm * dm; }
    sq += __shfl_xor(sq, 1);
    float rs = rsqrtf(sq * (1.f / 128.f) + EPSV);
    int chb = q * 64;
#pragma unroll
    for (int j = 0; j < 64; j += 2) {
      int ch = chb + j;
      bf16x2 p;
      p.x = (__bf16)((vals[j] - mu) * rs * lng[ch] + lnb[ch]);
      p.y = (__bf16)((vals[j + 1] - mu) * rs * lng[ch + 1] + lnb[ch + 1]);
      *(bf16x2*)&sA[row][ch] = p;
    }
  }
  __syncthreads();
  int lane = t & 63;
  int c15 = lane & 15, g = lane >> 4;
  int m0w = (t >> 6) * 32;
  f32x4 acc[16];
#pragma unroll
  for (int i = 0; i < 16; ++i) acc[i] = (f32x4){0.f, 0.f, 0.f, 0.f};
#pragma unroll
  for (int ks = 0; ks < 4; ++ks) {
    bf16x8 a0 = *(const bf16x8*)&sA[m0w + c15][ks * 32 + g * 8];
    bf16x8 a1 = *(const bf16x8*)&sA[m0w + 16 + c15][ks * 32 + g * 8];
#pragma unroll
    for (int nt = 0; nt < 8; ++nt) {
      bf16x8 bv = *(const bf16x8*)&sB[nt * 16 + c15][ks * 32 + g * 8];
      acc[nt] = __builtin_amdgcn_mfma_f32_16x16x32_bf16(a0, bv, acc[nt], 0, 0, 0);
      acc[8 + nt] = __builtin_amdgcn_mfma_f32_16x16x32_bf16(a1, bv, acc[8 + nt], 0, 0, 0);
    }
  }
#pragma unroll
  for (int mt = 0; mt < 2; ++mt) {
    int nbase = n0 + m0w + mt * 16 + g * 4;
#pragma unroll
    for (int r = 0; r < 4; ++r) {
      int n = nbase + r;
      float ps[4], pd[4];
#pragma unroll
      for (int hh = 0; hh < 4; ++hh) {
        float w0 = sAs[hh * 32 + c15], w1 = sAs[hh * 32 + 16 + c15];
        float d0 = sAd[hh * 32 + c15], d1 = sAd[hh * 32 + 16 + c15];
        float x0 = acc[mt * 8 + 2 * hh][r], x1 = acc[mt * 8 + 2 * hh + 1][r];
        ps[hh] = x0 * w0 + x1 * w1;
        pd[hh] = x0 * d0 + x1 * d1;
      }
#pragma unroll
      for (int m = 1; m < 16; m <<= 1) {
#pragma unroll
        for (int hh = 0; hh < 4; ++hh) {
          ps[hh] += __shfl_xor(ps[hh], m);
          pd[hh] += __shfl_xor(pd[hh], m);
        }
      }
      if (n < NN) {
        if (c15 == 0) {
          *(float4*)(asrc + (size_t)n * 4) = make_float4(ps[0], ps[1], ps[2], ps[3]);
          *(float4*)(adst + (size_t)n * 4) = make_float4(pd[0], pd[1], pd[2], pd[3]);
        }
        __bf16* op = xsb + (size_t)n * HC + c15;
#pragma unroll
        for (int nt = 0; nt < 8; ++nt) op[nt * 16] = (__bf16)acc[mt * 8 + nt][r];
      }
    }
  }
}

// wave per node: fused score + aggregation + self-loop + residual relu.
// Score computed once per (edge,head) by lane (head*16 + u), broadcast via __shfl.
__global__ __launch_bounds__(256) void k_aggr(const int* __restrict__ row_ptr, const unsigned* __restrict__ recd,
                                              int loff, const __bf16* __restrict__ xsb,
                                              const float* __restrict__ asrc, const float* __restrict__ adst,
                                              const float* __restrict__ bgi, float* __restrict__ h) {
  int wid = (blockIdx.x * 256 + threadIdx.x) >> 6;
  if (wid >= NN) return;
  int lane = threadIdx.x & 63;
  int ch0 = 2 * lane, head = lane >> 4;
  int um = lane & 7;        // score edge slot (2x redundant across bit3)
  int sbase = head << 4;    // shuffle source base: lanes sbase..sbase+7 hold scores
  int hs = head >> 1;
  int j0 = row_ptr[wid], j1 = row_ptr[wid + 1];
  float ad = adst[(size_t)wid * 4 + head];
  float acc0 = 0.f, acc1 = 0.f, dsum = 0.f, aes = 0.f;
  int j = j0;
  for (; j + 8 <= j1; j += 8) {
    int ss[8];
#pragma unroll
    for (int u = 0; u < 8; ++u) ss[u] = (int)recd[(size_t)(j + u) * 8];
    // my score: edge j+um, head
    unsigned aw = recd[(size_t)(j + um) * 8 + loff + hs];
    float av = (head & 1) ? bhi(aw) : blo(aw);
    float as = asrc[(size_t)ss[um] * 4 + head];
    float alpha = as + ad + av;
    alpha = alpha > 0.f ? alpha : NEGS * alpha;
    float em = __expf(alpha);
    aes += av;
    unsigned xv[8];
#pragma unroll
    for (int u = 0; u < 8; ++u) xv[u] = *(const unsigned*)(xsb + (size_t)ss[u] * HC + ch0);
#pragma unroll
    for (int u = 0; u < 8; ++u) {
      float e = __shfl(em, sbase + u);
      acc0 += e * blo(xv[u]);
      acc1 += e * bhi(xv[u]);
      dsum += e;
    }
  }
  // combine per-u-lane aes partials (full sum lands in every lane of the half-groups)
  aes += __shfl_xor(aes, 1);
  aes += __shfl_xor(aes, 2);
  aes += __shfl_xor(aes, 4);
  for (; j < j1; ++j) {
    const unsigned* rp = recd + (size_t)j * 8;
    int s0 = (int)rp[0];
    unsigned aw = rp[loff + hs];
    float v0 = (head & 1) ? bhi(aw) : blo(aw);
    float as0 = asrc[(size_t)s0 * 4 + head];
    unsigned x0 = *(const unsigned*)(xsb + (size_t)s0 * HC + ch0);
    float a0 = as0 + ad + v0;
    a0 = a0 > 0.f ? a0 : NEGS * a0;
    float e0 = __expf(a0);
    acc0 += e0 * blo(x0);
    acc1 += e0 * bhi(x0);
    dsum += e0;
    aes += v0;
  }
  int deg = j1 - j0;
  float aself = (deg > 0) ? aes / (float)deg : 0.f;
  float al = asrc[(size_t)wid * 4 + head] + ad + aself;
  al = al > 0.f ? al : NEGS * al;
  float exl = __expf(al);
  unsigned xv = *(const unsigned*)(xsb + (size_t)wid * HC + ch0);
  float inv = 1.f / (dsum + exl);
  float o0 = (acc0 + exl * blo(xv)) * inv;
  float o1 = (acc1 + exl * bhi(xv)) * inv;
  float* hp = h + (size_t)wid * HC;
  hp[ch0] += fmaxf(0.f, o0 + bgi[ch0]);
  hp[ch0 + 1] += fmaxf(0.f, o1 + bgi[ch0 + 1]);
}

__global__ __launch_bounds__(256) void k_emb(const float* __restrict__ h, float* __restrict__ emb) {
  int t = blockIdx.x * 256 + threadIdx.x;
  int stride = gridDim.x * 256;
  float s = 0.f;
  for (int i = t; i < NN * HC; i += stride) s += h[i];
  __shared__ float red[256];
  red[threadIdx.x] = s;
  __syncthreads();
  if (threadIdx.x < 128) {
    float v2 = red[threadIdx.x] + red[threadIdx.x + 128];
    atomicAdd(&emb[threadIdx.x], v2 * (1.f / NN));
  }
}

extern "C" void kernel_launch(void* const* d_in, const int* in_sizes, int n_in, void* d_out, int out_size,
                              void* d_ws, size_t ws_size, hipStream_t stream) {
  (void)in_sizes; (void)n_in; (void)out_size; (void)ws_size;
  const float* x = (const float*)d_in[0];
  const int* ei = (const int*)d_in[1];
  const float* ea = (const float*)d_in[2];
  const float* Wn = (const float*)d_in[3];
  const float* bn = (const float*)d_in[4];
  const float* We = (const float*)d_in[5];
  const float* be = (const float*)d_in[6];
  const float* lng = (const float*)d_in[7];
  const float* lnb = (const float*)d_in[8];
  const float* Wg = (const float*)d_in[9];
  const float* atts = (const float*)d_in[10];
  const float* attd = (const float*)d_in[11];
  const float* atte = (const float*)d_in[12];
  const float* Wed = (const float*)d_in[13];
  const float* bg = (const float*)d_in[14];
  float* h = (float*)d_out;
  float* emb = h + (size_t)NN * HC;

  char* w = (char*)d_ws;
  size_t off = 0;
  auto alloc = [&](size_t bytes) {
    void* p = w + off;
    off = (off + bytes + 255) & ~(size_t)255;
    return p;
  };
  __bf16* xsb = (__bf16*)alloc((size_t)NN * HC * 2);
  float* asrc = (float*)alloc((size_t)NN * 4 * 4);
  float* adst = (float*)alloc((size_t)NN * 4 * 4);
  int* cnt = (int*)alloc((size_t)NN * 4);
  int* row_ptr = (int*)alloc((size_t)(NN + 1) * 4);
  int* wr_ptr = (int*)alloc((size_t)NN * 4);
  int* bsum = (int*)alloc(256);
  int* stmp = (int*)alloc((size_t)NN * 4);
  uint4* rec = (uint4*)alloc((size_t)EE * 32);
  float* Pc = (float*)alloc(3 * 36 * 4);
  __bf16* wgt = (__bf16*)alloc((size_t)3 * 128 * 136 * 2);

  hipMemsetAsync(cnt, 0, (size_t)NN * 4, stream);
  hipMemsetAsync(emb, 0, HC * 4, stream);

  k_h0<<<cdiv(NN * HC, 256), 256, 0, stream>>>(x, Wn, bn, h);
  k_hist<<<cdiv(EE, 256), 256, 0, stream>>>(ei, cnt);
  int nb = cdiv(NN, 1024);
  k_scan1<<<nb, 1024, 0, stream>>>(cnt, stmp, bsum);
  k_scan2<<<1, 64, 0, stream>>>(bsum, nb);
  k_scan3<<<nb, 1024, 0, stream>>>(stmp, bsum, row_ptr, wr_ptr);
  k_wcoef<<<1, 128, 0, stream>>>(We, be, Wed, atte, Pc);
  k_prep<<<cdiv(3 * 128 * 136, 256), 256, 0, stream>>>(Wg, wgt);
  k_build<<<cdiv(EE, 256), 256, 0, stream>>>(ei, ea, Pc, wr_ptr, rec);

  for (int i = 0; i < 3; ++i) {
    k_node<<<cdiv(NN, 128), 256, 0, stream>>>(h, lng + i * HC, lnb + i * HC, wgt + (size_t)i * 128 * 136,
                                              atts + i * HC, attd + i * HC, xsb, asrc, adst);
    k_aggr<<<cdiv(NN, 4), 256, 0, stream>>>(row_ptr, (const unsigned*)rec, 1 + 2 * i, xsb, asrc, adst,
                                            bg + i * HC, h);
  }
  k_emb<<<512, 256, 0, stream>>>(h, emb);
}